// Round 4
// baseline (380.457 us; speedup 1.0000x reference)
//
#include <hip/hip_runtime.h>
#include <hip/hip_bf16.h>

#define T_STEPS 301
#define IN_DIM  40
#define LOG2E   1.44269504088896340736f

typedef __attribute__((ext_vector_type(8))) short bf16x8;
typedef __attribute__((ext_vector_type(4))) float f32x4;
typedef unsigned short ushort_t;
typedef unsigned int uint_t;

__device__ __forceinline__ ushort_t bf16_rn(float f) {
  uint_t u = __float_as_uint(f);
  uint_t r = u + 0x7FFFu + ((u >> 16) & 1u);
  return (ushort_t)(r >> 16);
}
__device__ __forceinline__ void split1(float f, ushort_t& hi, ushort_t& lo) {
  hi = bf16_rn(f);
  float fhi = __uint_as_float((uint_t)hi << 16);
  lo = bf16_rn(f - fhi);
}
__device__ __forceinline__ void split8(const float* v, bf16x8& hi, bf16x8& lo) {
#pragma unroll
  for (int e = 0; e < 8; ++e) {
    ushort_t h, l;
    split1(v[e], h, l);
    hi[e] = (short)h;
    lo[e] = (short)l;
  }
}
__device__ __forceinline__ uint_t pack_bf2(float a, float b) {
  __hip_bfloat162 t = __float22bfloat162_rn(make_float2(a, b));
  union { __hip_bfloat162 h; uint_t u; } c;
  c.h = t;
  return c.u;
}
__device__ __forceinline__ bf16x8 cvt8(const float4 a, const float4 b) {
  union { bf16x8 v; uint_t u[4]; } r;
  r.u[0] = pack_bf2(a.x, a.y);
  r.u[1] = pack_bf2(a.z, a.w);
  r.u[2] = pack_bf2(b.x, b.y);
  r.u[3] = pack_bf2(b.z, b.w);
  return r.v;
}

// 512 blocks x 256 thr (4 waves) -> 2 independent blocks per CU (latency hiding).
// Block = 8 batches, occupying D rows {0,1,4,5,8,9,12,13} (row&2==0); other rows
// stay zero. Wave w owns hidden strip n in [16w,16w+16), all 4 gates -> activation
// fully in-register. Weights prescaled by log2e (2*log2e for g) -> exp2 activations.
// h recurrence: 3-product split-bf16; x projection: single bf16 x, 2-product weights.
__global__ __launch_bounds__(256, 2)
void lstm_m8(const float* __restrict__ x, const float* __restrict__ w_ih,
             const float* __restrict__ w_hh, const float* __restrict__ b_ih,
             const float* __restrict__ b_hh, const float* __restrict__ w_clf,
             const float* __restrict__ b_clf, float* __restrict__ out) {
  __shared__ ushort_t hbuf[2][2][16][64];   // [buf][hi/lo][row][chunks] 8 KB
  __shared__ float red[64][9];

  const int tid = threadIdx.x;
  const int l   = tid & 63;
  const int w   = tid >> 6;       // n-strip id 0..3
  const int col = l & 15;         // A/D row index side: batch row ; B/D col: n'
  const int g16 = l >> 4;         // k-group / D row group
  const int n   = w * 16 + col;   // hidden index

  // batch mapping for A-side (x loads): row 'col' valid iff (col&2)==0
  const bool avalid = ((col & 2) == 0);
  const int bloc = ((col >> 2) << 1) | (col & 1);        // 0..7
  const int gb = blockIdx.x * 8 + (avalid ? bloc : 0);   // aliased for invalid rows

  const float gscale[4] = {LOG2E, LOG2E, 2.0f * LOG2E, LOG2E};

  // ---- weights in registers (prescaled, split) ----
  bf16x8 whh_hi[4][2], whh_lo[4][2], wih_hi[4][2], wih_lo[4][2];
  float biasv[4];
#pragma unroll
  for (int c = 0; c < 4; ++c) {
    const float s = gscale[c];
    const float* wr = w_hh + (size_t)(c * 64 + n) * 64;
#pragma unroll
    for (int kc = 0; kc < 2; ++kc) {
      float v[8];
      *(float4*)&v[0] = *(const float4*)(wr + kc * 32 + g16 * 8);
      *(float4*)&v[4] = *(const float4*)(wr + kc * 32 + g16 * 8 + 4);
#pragma unroll
      for (int e = 0; e < 8; ++e) v[e] *= s;
      split8(v, whh_hi[c][kc], whh_lo[c][kc]);
    }
    const float* wir = w_ih + (size_t)(c * 64 + n) * IN_DIM;
    {
      float v[8];
      *(float4*)&v[0] = *(const float4*)(wir + g16 * 8);
      *(float4*)&v[4] = *(const float4*)(wir + g16 * 8 + 4);
#pragma unroll
      for (int e = 0; e < 8; ++e) v[e] *= s;
      split8(v, wih_hi[c][0], wih_lo[c][0]);
    }
    {
      float v[8] = {0, 0, 0, 0, 0, 0, 0, 0};
      if (g16 == 0) {
        *(float4*)&v[0] = *(const float4*)(wir + 32);
        *(float4*)&v[4] = *(const float4*)(wir + 36);
#pragma unroll
        for (int e = 0; e < 8; ++e) v[e] *= s;
      }
      split8(v, wih_hi[c][1], wih_lo[c][1]);
    }
    biasv[c] = (b_ih[c * 64 + n] + b_hh[c * 64 + n]) * s;
  }

  // zero ALL of hbuf (both buffers: never-written rows must stay 0)
  {
    uint_t* hz = (uint_t*)&hbuf[0][0][0][0];
    for (int i = tid; i < 2048; i += 256) hz[i] = 0;
  }
  __syncthreads();

  float cc0 = 0.f, cc1 = 0.f;        // cell state for rows r=0,1
  float a0 = 0.f, a1 = 0.f;          // classifier partials
  float wc_cur = w_clf[n];

  // x A-frag f32 prefetch regs (step 0)
  const float* xp = x + (size_t)gb * T_STEPS * IN_DIM + g16 * 8;
  float4 xa0 = *(const float4*)xp;
  float4 xa1 = *(const float4*)(xp + 4);
  float4 xb0 = make_float4(0, 0, 0, 0), xb1 = make_float4(0, 0, 0, 0);
  if (g16 == 0) {
    xb0 = *(const float4*)(xp + 32);
    xb1 = *(const float4*)(xp + 36);
  }

  const int row0 = g16 * 4;          // D rows this lane activates: row0, row0+1
  const int idx0 = (((n >> 3) ^ (row0 & 7)) * 8) + (n & 7);
  const int idx1 = (((n >> 3) ^ ((row0 + 1) & 7)) * 8) + (n & 7);

  for (int t = 0; t < T_STEPS; ++t) {
    const int br = t & 1, bw = br ^ 1;

    // h A-frags (issue LDS reads first; x-proj below doesn't need them)
    bf16x8 ah[2], al[2];
#pragma unroll
    for (int kc = 0; kc < 2; ++kc) {
      const int cj = (kc * 4 + g16) ^ (col & 7);
      ah[kc] = *(const bf16x8*)&hbuf[br][0][col][cj * 8];
      al[kc] = *(const bf16x8*)&hbuf[br][1][col][cj * 8];
    }

    f32x4 acc[4];
#pragma unroll
    for (int c = 0; c < 4; ++c) acc[c] = (f32x4){biasv[c], biasv[c], biasv[c], biasv[c]};

    // x projection (single-bf16 x, 2-product weights) — independent of h
    bf16x8 xf0 = cvt8(xa0, xa1);
    bf16x8 xf1 = cvt8(xb0, xb1);
#pragma unroll
    for (int c = 0; c < 4; ++c) {
      acc[c] = __builtin_amdgcn_mfma_f32_16x16x32_bf16(xf0, wih_hi[c][0], acc[c], 0, 0, 0);
      acc[c] = __builtin_amdgcn_mfma_f32_16x16x32_bf16(xf0, wih_lo[c][0], acc[c], 0, 0, 0);
      acc[c] = __builtin_amdgcn_mfma_f32_16x16x32_bf16(xf1, wih_hi[c][1], acc[c], 0, 0, 0);
      acc[c] = __builtin_amdgcn_mfma_f32_16x16x32_bf16(xf1, wih_lo[c][1], acc[c], 0, 0, 0);
    }

    // prefetch next x + next w_clf (stays in flight across the raw barrier)
    float wcn = wc_cur;
    if (t + 1 < T_STEPS) {
      xp += IN_DIM;
      xa0 = *(const float4*)xp;
      xa1 = *(const float4*)(xp + 4);
      if (g16 == 0) {
        xb0 = *(const float4*)(xp + 32);
        xb1 = *(const float4*)(xp + 36);
      }
      wcn = w_clf[(t + 1) * 64 + n];
    }

    // recurrent 3-product
#pragma unroll
    for (int c = 0; c < 4; ++c) {
#pragma unroll
      for (int kc = 0; kc < 2; ++kc) {
        acc[c] = __builtin_amdgcn_mfma_f32_16x16x32_bf16(ah[kc], whh_hi[c][kc], acc[c], 0, 0, 0);
        acc[c] = __builtin_amdgcn_mfma_f32_16x16x32_bf16(al[kc], whh_hi[c][kc], acc[c], 0, 0, 0);
        acc[c] = __builtin_amdgcn_mfma_f32_16x16x32_bf16(ah[kc], whh_lo[c][kc], acc[c], 0, 0, 0);
      }
    }

    // activations on valid rows only (r = 0,1); z already scaled by log2e
    float h0, h1;
    {
      const float ig = __builtin_amdgcn_rcpf(1.0f + __builtin_amdgcn_exp2f(-acc[0][0]));
      const float fg = __builtin_amdgcn_rcpf(1.0f + __builtin_amdgcn_exp2f(-acc[1][0]));
      const float gg = 1.0f - 2.0f * __builtin_amdgcn_rcpf(1.0f + __builtin_amdgcn_exp2f(acc[2][0]));
      const float og = __builtin_amdgcn_rcpf(1.0f + __builtin_amdgcn_exp2f(-acc[3][0]));
      cc0 = fg * cc0 + ig * gg;
      const float tc = 1.0f - 2.0f * __builtin_amdgcn_rcpf(1.0f + __builtin_amdgcn_exp2f(cc0 * (2.0f * LOG2E)));
      h0 = og * tc;
      a0 += h0 * wc_cur;
    }
    {
      const float ig = __builtin_amdgcn_rcpf(1.0f + __builtin_amdgcn_exp2f(-acc[0][1]));
      const float fg = __builtin_amdgcn_rcpf(1.0f + __builtin_amdgcn_exp2f(-acc[1][1]));
      const float gg = 1.0f - 2.0f * __builtin_amdgcn_rcpf(1.0f + __builtin_amdgcn_exp2f(acc[2][1]));
      const float og = __builtin_amdgcn_rcpf(1.0f + __builtin_amdgcn_exp2f(-acc[3][1]));
      cc1 = fg * cc1 + ig * gg;
      const float tc = 1.0f - 2.0f * __builtin_amdgcn_rcpf(1.0f + __builtin_amdgcn_exp2f(cc1 * (2.0f * LOG2E)));
      h1 = og * tc;
      a1 += h1 * wc_cur;
    }
    wc_cur = wcn;

    // split h (packed) and store to next buffer
    {
      const uint_t hp = pack_bf2(h0, h1);
      const float hi0 = __uint_as_float(hp << 16);
      const float hi1 = __uint_as_float(hp & 0xFFFF0000u);
      const uint_t lp = pack_bf2(h0 - hi0, h1 - hi1);
      hbuf[bw][0][row0][idx0]     = (ushort_t)(hp & 0xFFFFu);
      hbuf[bw][0][row0 + 1][idx1] = (ushort_t)(hp >> 16);
      hbuf[bw][1][row0][idx0]     = (ushort_t)(lp & 0xFFFFu);
      hbuf[bw][1][row0 + 1][idx1] = (ushort_t)(lp >> 16);
    }

    // drain LDS only (NOT vmcnt: x prefetch stays in flight), then barrier
    asm volatile("s_waitcnt lgkmcnt(0)\n\ts_barrier" ::: "memory");
  }

  // ---- epilogue ----
  red[n][g16 * 2 + 0] = a0;
  red[n][g16 * 2 + 1] = a1;
  __syncthreads();
  if (tid < 8) {
    float s = b_clf[0];
#pragma unroll 8
    for (int j = 0; j < 64; ++j) s += red[j][tid];
    out[blockIdx.x * 8 + tid] = s;
  }
}

extern "C" void kernel_launch(void* const* d_in, const int* in_sizes, int n_in,
                              void* d_out, int out_size, void* d_ws, size_t ws_size,
                              hipStream_t stream) {
  const float* x     = (const float*)d_in[0];
  const float* w_ih  = (const float*)d_in[1];
  const float* w_hh  = (const float*)d_in[2];
  const float* b_ih  = (const float*)d_in[3];
  const float* b_hh  = (const float*)d_in[4];
  const float* w_clf = (const float*)d_in[5];
  const float* b_clf = (const float*)d_in[6];
  float* out = (float*)d_out;

  lstm_m8<<<512, 256, 0, stream>>>(x, w_ih, w_hh, b_ih, b_hh, w_clf, b_clf, out);
}

// Round 6
// 190.804 us; speedup vs baseline: 1.9940x; 1.9940x over previous
//
#include <hip/hip_runtime.h>

#define T_STEPS 301
#define IN_DIM  40
#define LOG2E   1.44269504088896340736f

typedef __attribute__((ext_vector_type(8))) _Float16 f16x8;
typedef __attribute__((ext_vector_type(4))) float f32x4;
typedef unsigned short ushort_t;
typedef unsigned int uint_t;

__device__ __forceinline__ f16x8 cvt8h(const float4 a, const float4 b) {
  f16x8 r;
  r[0] = (_Float16)a.x; r[1] = (_Float16)a.y; r[2] = (_Float16)a.z; r[3] = (_Float16)a.w;
  r[4] = (_Float16)b.x; r[5] = (_Float16)b.y; r[6] = (_Float16)b.z; r[7] = (_Float16)b.w;
  return r;
}

// z inputs pre-scaled by log2e (2*log2e for g-gate), so activations use exp2.
__device__ __forceinline__ float lstm_act(float zi, float zf, float zg, float zo, float& cc) {
  const float ig = __builtin_amdgcn_rcpf(1.0f + __builtin_amdgcn_exp2f(-zi));
  const float fg = __builtin_amdgcn_rcpf(1.0f + __builtin_amdgcn_exp2f(-zf));
  const float gg = 1.0f - 2.0f * __builtin_amdgcn_rcpf(1.0f + __builtin_amdgcn_exp2f(zg));
  const float og = __builtin_amdgcn_rcpf(1.0f + __builtin_amdgcn_exp2f(-zo));
  cc = fg * cc + ig * gg;
  const float tc = 1.0f - 2.0f * __builtin_amdgcn_rcpf(1.0f + __builtin_amdgcn_exp2f(cc * (2.0f * LOG2E)));
  return og * tc;
}

// 512 blocks x 256 thr (4 waves), 2 independent blocks/CU (proven R4 overlap).
// Block = 8 batches. A/D rows: row = 4*(slot>>1) + 2*toff + (slot&1): rows with
// (row&2)==0 carry timestep t (the recurrence), rows with (row&2)==1 carry
// timestep t+1 FOR THE INPUT PROJECTION ONLY (their h-rows stay zero, so the
// recurrent MFMA passes xw[t+1] through untouched in acc regs r2,r3).
// Wave w owns hidden strip n in [16w,16w+16), all 4 gates -> in-register acts.
// All operands fp16 single-product; weights prescaled by log2e (2log2e for g).
__global__ __launch_bounds__(256, 2)
void lstm_f16(const float* __restrict__ x, const float* __restrict__ w_ih,
              const float* __restrict__ w_hh, const float* __restrict__ b_ih,
              const float* __restrict__ b_hh, const float* __restrict__ w_clf,
              const float* __restrict__ b_clf, float* __restrict__ out) {
  __shared__ ushort_t hbuf[2][16][64];   // fp16 h, XOR-swizzled chunks, 4 KB
  __shared__ float red[64][9];

  const int tid  = threadIdx.x;
  const int l    = tid & 63;
  const int w    = tid >> 6;        // n-strip id
  const int arow = l & 15;          // A/D row this lane reads; D col = arow
  const int g16  = l >> 4;          // k-group / D row group
  const int n    = w * 16 + arow;   // hidden index (B/D col space)

  const float gscale[4] = {LOG2E, LOG2E, 2.0f * LOG2E, LOG2E};

  // ---- weights in registers (fp16, prescaled) ----
  f16x8 whh[4][2], wih[4][2];
  float biasv[4];
#pragma unroll
  for (int c = 0; c < 4; ++c) {
    const float s = gscale[c];
    const float* wr = w_hh + (size_t)(c * 64 + n) * 64;
#pragma unroll
    for (int kc = 0; kc < 2; ++kc) {
      float4 v0 = *(const float4*)(wr + kc * 32 + g16 * 8);
      float4 v1 = *(const float4*)(wr + kc * 32 + g16 * 8 + 4);
      v0.x *= s; v0.y *= s; v0.z *= s; v0.w *= s;
      v1.x *= s; v1.y *= s; v1.z *= s; v1.w *= s;
      whh[c][kc] = cvt8h(v0, v1);
    }
    const float* wir = w_ih + (size_t)(c * 64 + n) * IN_DIM;
    {
      float4 v0 = *(const float4*)(wir + g16 * 8);       // k = 8*g16..+8 <= 31
      float4 v1 = *(const float4*)(wir + g16 * 8 + 4);
      v0.x *= s; v0.y *= s; v0.z *= s; v0.w *= s;
      v1.x *= s; v1.y *= s; v1.z *= s; v1.w *= s;
      wih[c][0] = cvt8h(v0, v1);
    }
    {
      float4 v0 = make_float4(0, 0, 0, 0), v1 = make_float4(0, 0, 0, 0);
      if (g16 == 0) {                                    // k = 32..39
        v0 = *(const float4*)(wir + 32);
        v1 = *(const float4*)(wir + 36);
        v0.x *= s; v0.y *= s; v0.z *= s; v0.w *= s;
        v1.x *= s; v1.y *= s; v1.z *= s; v1.w *= s;
      }
      wih[c][1] = cvt8h(v0, v1);
    }
    biasv[c] = (b_ih[c * 64 + n] + b_hh[c * 64 + n]) * s;
  }

  // zero both h buffers (rows with row&2==1 must stay zero forever)
  {
    uint_t* hz = (uint_t*)&hbuf[0][0][0];
    for (int i = tid; i < 1024; i += 256) hz[i] = 0;
  }
  __syncthreads();

  // x lane mapping: row -> (batch slot, time offset)
  const int slot = ((arow >> 2) << 1) | (arow & 1);   // 0..7
  const int toff = (arow >> 1) & 1;                   // 0: time t, 1: time t+1
  const int gb   = blockIdx.x * 8 + slot;
  const float* xbase = x + (size_t)gb * T_STEPS * IN_DIM;

  // prefetch x for pair t=0 (lane's time = min(toff, last))
  float4 xa0, xa1, xb0 = make_float4(0, 0, 0, 0), xb1 = make_float4(0, 0, 0, 0);
  {
    const int tm = toff < T_STEPS ? toff : T_STEPS - 1;
    const float* xp = xbase + tm * IN_DIM + g16 * 8;
    xa0 = *(const float4*)xp;
    xa1 = *(const float4*)(xp + 4);
    if (g16 == 0) {
      xb0 = *(const float4*)(xbase + tm * IN_DIM + 32);
      xb1 = *(const float4*)(xbase + tm * IN_DIM + 36);
    }
  }

  f32x4 zacc[4];                        // persistent across a step pair
  float cc0 = 0.f, cc1 = 0.f, a0 = 0.f, a1 = 0.f;
  float wc_cur = w_clf[n];

  const int row0 = g16 * 4, row1 = row0 + 1;   // valid D rows (row&2==0)
  const int wo0 = row0 * 64 + ((((n >> 3) ^ (row0 & 7)) << 3) | (n & 7));
  const int wo1 = row1 * 64 + ((((n >> 3) ^ (row1 & 7)) << 3) | (n & 7));
  ushort_t* hflat = &hbuf[0][0][0];

  for (int t = 0; t < T_STEPS; ++t) {
    const int rb = t & 1, wb = rb ^ 1;

    // h A-frags first (they carry the LDS latency)
    f16x8 ah0, ah1;
    {
      const int cj0 = g16 ^ (arow & 7);          // kc=0 logical chunk g16
      const int cj1 = (4 + g16) ^ (arow & 7);    // kc=1 logical chunk 4+g16
      ah0 = *(const f16x8*)&hbuf[rb][arow][cj0 * 8];
      ah1 = *(const f16x8*)&hbuf[rb][arow][cj1 * 8];
    }

    f32x4 zcur[4];
    if ((t & 1) == 0) {
      // xw for pair (t, t+1): rows toff=0 get time t, toff=1 get time t+1
      const f16x8 xf0 = cvt8h(xa0, xa1);
      const f16x8 xf1 = cvt8h(xb0, xb1);
#pragma unroll
      for (int c = 0; c < 4; ++c) {
        zacc[c] = (f32x4){biasv[c], biasv[c], biasv[c], biasv[c]};
        zacc[c] = __builtin_amdgcn_mfma_f32_16x16x32_f16(xf0, wih[c][0], zacc[c], 0, 0, 0);
        zacc[c] = __builtin_amdgcn_mfma_f32_16x16x32_f16(xf1, wih[c][1], zacc[c], 0, 0, 0);
      }
      // prefetch x for pair t+2 (stays in flight across barriers)
      if (t + 2 < T_STEPS) {
        const int tm = (t + 2 + toff < T_STEPS) ? t + 2 + toff : T_STEPS - 1;
        const float* xp = xbase + tm * IN_DIM + g16 * 8;
        xa0 = *(const float4*)xp;
        xa1 = *(const float4*)(xp + 4);
        if (g16 == 0) {
          xb0 = *(const float4*)(xbase + tm * IN_DIM + 32);
          xb1 = *(const float4*)(xbase + tm * IN_DIM + 36);
        }
      }
      // recurrence in place: h rows for (row&2)==1 are zero -> r2,r3 = xw[t+1] preserved
#pragma unroll
      for (int c = 0; c < 4; ++c) {
        zacc[c] = __builtin_amdgcn_mfma_f32_16x16x32_f16(ah0, whh[c][0], zacc[c], 0, 0, 0);
        zacc[c] = __builtin_amdgcn_mfma_f32_16x16x32_f16(ah1, whh[c][1], zacc[c], 0, 0, 0);
        zcur[c] = zacc[c];
      }
    } else {
      // odd step: init from preserved xw[t] (r2,r3 of zacc)
#pragma unroll
      for (int c = 0; c < 4; ++c) {
        f32x4 acc = __builtin_shufflevector(zacc[c], zacc[c], 2, 3, 2, 3);
        acc = __builtin_amdgcn_mfma_f32_16x16x32_f16(ah0, whh[c][0], acc, 0, 0, 0);
        acc = __builtin_amdgcn_mfma_f32_16x16x32_f16(ah1, whh[c][1], acc, 0, 0, 0);
        zcur[c] = acc;
      }
    }

    const float wcn = (t + 1 < T_STEPS) ? w_clf[(t + 1) * 64 + n] : wc_cur;

    // activations on valid rows r=0,1 (batches 2*g16, 2*g16+1)
    const float h0 = lstm_act(zcur[0][0], zcur[1][0], zcur[2][0], zcur[3][0], cc0);
    const float h1 = lstm_act(zcur[0][1], zcur[1][1], zcur[2][1], zcur[3][1], cc1);
    a0 += h0 * wc_cur;
    a1 += h1 * wc_cur;
    wc_cur = wcn;

    // store fp16 h for next step
    {
      union { _Float16 h; ushort_t u; } u0, u1;
      u0.h = (_Float16)h0;
      u1.h = (_Float16)h1;
      ushort_t* hb = hflat + wb * 1024;
      hb[wo0] = u0.u;
      hb[wo1] = u1.u;
    }
    // drain LDS only (x prefetch stays in flight), then barrier
    asm volatile("s_waitcnt lgkmcnt(0)\n\ts_barrier" ::: "memory");
  }

  // ---- epilogue: reduce classifier partials over hidden dim ----
  red[n][g16 * 2 + 0] = a0;
  red[n][g16 * 2 + 1] = a1;
  __syncthreads();
  if (tid < 8) {
    float s = b_clf[0];
#pragma unroll 8
    for (int j = 0; j < 64; ++j) s += red[j][tid];
    out[blockIdx.x * 8 + tid] = s;
  }
}

extern "C" void kernel_launch(void* const* d_in, const int* in_sizes, int n_in,
                              void* d_out, int out_size, void* d_ws, size_t ws_size,
                              hipStream_t stream) {
  const float* x     = (const float*)d_in[0];
  const float* w_ih  = (const float*)d_in[1];
  const float* w_hh  = (const float*)d_in[2];
  const float* b_ih  = (const float*)d_in[3];
  const float* b_hh  = (const float*)d_in[4];
  const float* w_clf = (const float*)d_in[5];
  const float* b_clf = (const float*)d_in[6];
  float* out = (float*)d_out;

  lstm_f16<<<512, 256, 0, stream>>>(x, w_ih, w_hh, b_ih, b_hh, w_clf, b_clf, out);
}